// Round 2
// baseline (562.887 us; speedup 1.0000x reference)
//
#include <hip/hip_runtime.h>

// SVDQuantLinear: out[m,n] = x[m,:] . (w_q[n,:]*w_scale[n]) + bias[n] + lora
// Fold rank-32 LoRA into dequantized W (fp32, one bf16 round) -> one bf16 GEMM.
// R1: XOR-swizzled LDS, R2: 32x32x16 + fused prep.
// R3: 256x256/BK=32 ring, counted vmcnt(8), setprio, XCD swizzle ->
//     conflicts 0, MfmaUtil 48%, gemm 350->258us.
// R4 (this round): 2-phase per-K-tile interleave (template T3 fine structure):
//     phase = {ds_read 16-MFMA subtile | stage half of t+3 | barrier |
//              lgkmcnt(0) | setprio(1) 16xMFMA setprio(0) | barrier},
//     single counted vmcnt(8) gate per K-tile. Reads of phase p overlap the
//     MFMA pipe drain of phase p-1; waves stay phase-locked (m196/m201).

#define M_DIM 8192   // B*S
#define N_DIM 4096   // D_OUT
#define K_DIM 4096   // D_IN
#define R_DIM 32

#define BM 256
#define BN 256
#define BK 32                 // 64 B per row in LDS
#define NT (K_DIM / BK)       // 128 k-tiles
#define NSLOT 4               // LDS ring depth: 4 * (16KB A + 16KB B) = 128 KiB

typedef short bf16x8 __attribute__((ext_vector_type(8)));
typedef float f32x4 __attribute__((ext_vector_type(4)));
typedef unsigned short u16x8 __attribute__((ext_vector_type(8)));

#define GLOBAL_AS __attribute__((address_space(1)))
#define LDS_AS __attribute__((address_space(3)))

__device__ __forceinline__ unsigned short f2bf(float f) {
  union { float f; unsigned u; } v;
  v.f = f;
  unsigned u = v.u;
  u += 0x7fffu + ((u >> 16) & 1u);  // RNE (finite inputs)
  return (unsigned short)(u >> 16);
}

// ---------------- cast x -> bf16 (memory-bound; 192 MB ~ 31 us ideal) ------
__global__ void cast_kernel(const float* __restrict__ x,
                            unsigned short* __restrict__ Xbf) {
  size_t i = ((size_t)blockIdx.x * 256 + threadIdx.x) * 8;
  float4 v0 = *(const float4*)(x + i);
  float4 v1 = *(const float4*)(x + i + 4);
  u16x8 o;
  o[0] = f2bf(v0.x); o[1] = f2bf(v0.y); o[2] = f2bf(v0.z); o[3] = f2bf(v0.w);
  o[4] = f2bf(v1.x); o[5] = f2bf(v1.y); o[6] = f2bf(v1.z); o[7] = f2bf(v1.w);
  *(u16x8*)(Xbf + i) = o;
}

// ---------------- fold W_eff = wq*scale + lora_B*diag(S)*lora_A -> bf16 ----
__global__ void fold_kernel(const int* __restrict__ wq,
                            const float* __restrict__ wscale,
                            const float* __restrict__ lA,
                            const float* __restrict__ lS,
                            const float* __restrict__ lB,
                            unsigned short* __restrict__ Wbf) {
  __shared__ float bs[4][32];
  const int tid = threadIdx.x;
  const int o0 = (int)(blockIdx.x >> 1) * 4;
  const int i0 = (int)(blockIdx.x & 1) * 2048 + tid * 8;

  if (tid < 128) {
    int o = tid >> 5, r = tid & 31;
    bs[o][r] = lB[(size_t)(o0 + o) * R_DIM + r] * lS[r];
  }
  __syncthreads();

  float acc[4][8];
#pragma unroll
  for (int o = 0; o < 4; ++o)
#pragma unroll
    for (int j = 0; j < 8; ++j) acc[o][j] = 0.f;

  for (int r = 0; r < R_DIM; ++r) {
    float4 a0 = *(const float4*)(lA + (size_t)r * K_DIM + i0);
    float4 a1 = *(const float4*)(lA + (size_t)r * K_DIM + i0 + 4);
    float av[8] = {a0.x, a0.y, a0.z, a0.w, a1.x, a1.y, a1.z, a1.w};
#pragma unroll
    for (int o = 0; o < 4; ++o) {
      float b = bs[o][r];
#pragma unroll
      for (int j = 0; j < 8; ++j) acc[o][j] += b * av[j];
    }
  }

#pragma unroll
  for (int o = 0; o < 4; ++o) {
    float sc = wscale[o0 + o];
    const int* qp = wq + (size_t)(o0 + o) * K_DIM + i0;
    int4 q0 = *(const int4*)qp;
    int4 q1 = *(const int4*)(qp + 4);
    int qv[8] = {q0.x, q0.y, q0.z, q0.w, q1.x, q1.y, q1.z, q1.w};
    u16x8 ov;
#pragma unroll
    for (int j = 0; j < 8; ++j) ov[j] = f2bf(acc[o][j] + (float)qv[j] * sc);
    *(u16x8*)(Wbf + (size_t)(o0 + o) * K_DIM + i0) = ov;
  }
}

// ---------------- main GEMM: C = Xbf * Wbf^T + bias ------------------------
// 256x256 tile, BK=32, 512 thr = 8 waves (2M x 4N), wave = 128x64 output =
// 8x4 frags of 16x16x32 MFMA. 4-slot LDS ring; stage t+3 while computing t;
// counted vmcnt(8) gate once per K-tile (2 k-tiles in flight across barriers).
// Per K-tile: 2 phases of 16 MFMA with interleaved ds_read / half-staging.
// LDS: 16B line (row, sl) holds k-group g = sl ^ ((row>>1)&3); staging keeps
// LDS dest linear and permutes the per-lane GLOBAL k-offset (rule #21).
__global__ __launch_bounds__(512, 2) void gemm_bias_kernel(
    const unsigned short* __restrict__ A,   // [M, K] bf16 bits
    const unsigned short* __restrict__ B,   // [N, K] bf16 bits
    const float* __restrict__ bias,         // [N]
    float* __restrict__ C) {                // [M, N]
  __shared__ __align__(16) unsigned short sA[NSLOT][BM * BK];  // 4 x 16 KiB
  __shared__ __align__(16) unsigned short sB[NSLOT][BN * BK];  // 4 x 16 KiB

  const int tid = threadIdx.x;
  const int lane = tid & 63;
  const int wv = tid >> 6;      // 0..7
  const int wm = wv >> 2;       // 0..1
  const int wn = wv & 3;        // 0..3

  // T1: bijective XCD swizzle (grid = 512 = 8*64). XCD x owns 2 B-panels.
  const int bid = (int)blockIdx.x;
  const int s = ((bid & 7) << 6) + (bid >> 3);
  const int bn_ = s >> 5;       // 0..15
  const int bm_ = s & 31;       // 0..31
  const size_t m0 = (size_t)bm_ * BM;
  const size_t n0 = (size_t)bn_ * BN;

  // ---- staging: lane l -> local row l>>2, 16B slot l&3,
  // global k-group (l&3)^((l>>3)&3); LDS dest linear (wave-uniform base).
  const int lrow = lane >> 2;                                  // 0..15
  const int gsl = (((lane & 3) ^ ((lane >> 3) & 3))) * 8;      // k elems
  const int r0 = (wv * 2) * 16 + lrow;                         // chunk c=0 row
  const unsigned short* gA0 = A + (m0 + r0) * (size_t)K_DIM + gsl;
  const unsigned short* gA1 = gA0 + 16 * (size_t)K_DIM;
  const unsigned short* gB0 = B + (n0 + r0) * (size_t)K_DIM + gsl;
  const unsigned short* gB1 = gB0 + 16 * (size_t)K_DIM;
  const int ch0 = (wv * 2 + 0) * 512;   // LDS chunk bases (shorts, 1KB each)
  const int ch1 = (wv * 2 + 1) * 512;

#define STAGE_ALL(kt, sl_)                                                    \
  do {                                                                        \
    const size_t ko = (size_t)(kt)*BK;                                        \
    __builtin_amdgcn_global_load_lds((const GLOBAL_AS void*)(gA0 + ko),       \
                                     (LDS_AS void*)(&sA[sl_][ch0]), 16, 0, 0);\
    __builtin_amdgcn_global_load_lds((const GLOBAL_AS void*)(gA1 + ko),       \
                                     (LDS_AS void*)(&sA[sl_][ch1]), 16, 0, 0);\
    __builtin_amdgcn_global_load_lds((const GLOBAL_AS void*)(gB0 + ko),       \
                                     (LDS_AS void*)(&sB[sl_][ch0]), 16, 0, 0);\
    __builtin_amdgcn_global_load_lds((const GLOBAL_AS void*)(gB1 + ko),       \
                                     (LDS_AS void*)(&sB[sl_][ch1]), 16, 0, 0);\
  } while (0)

  // ---- read addressing (16x16x32 frag: m = lane&15, k = (lane>>4)*8+j)
  const int rdrow = lane & 15;
  const int slot4 = (lane >> 4) ^ ((lane >> 1) & 3);           // swizzled slot
  const int aoff = (wm * 128 + rdrow) * BK + slot4 * 8;        // + mf*512
  const int boff = (wn * 64 + rdrow) * BK + slot4 * 8;         // + nf*512

  f32x4 acc[8][4];
#pragma unroll
  for (int mf = 0; mf < 8; ++mf)
#pragma unroll
    for (int nf = 0; nf < 4; ++nf) acc[mf][nf] = (f32x4){0.f, 0.f, 0.f, 0.f};

  // ---- prologue: 3 k-tiles in flight; wait only for tile 0 (vmcnt(8)).
  STAGE_ALL(0, 0);
  STAGE_ALL(1, 1);
  STAGE_ALL(2, 2);
  asm volatile("s_waitcnt vmcnt(8)" ::: "memory");
  __builtin_amdgcn_s_barrier();
  asm volatile("" ::: "memory");

  for (int t = 0; t < NT; ++t) {
    const int sl = t & 3;
    const int slw = (t + 3) & 3;
    const bool st = (t + 3 < NT);
    const size_t ko = (size_t)(t + 3) * BK;
    bf16x8 af0[4], af1[4], bfr[4];

    // ================= phase 0: frags {mf0-3 x nf0-3} ======================
#pragma unroll
    for (int mf = 0; mf < 4; ++mf)
      af0[mf] = *(const bf16x8*)&sA[sl][aoff + mf * 512];
#pragma unroll
    for (int nf = 0; nf < 4; ++nf)
      bfr[nf] = *(const bf16x8*)&sB[sl][boff + nf * 512];
    if (st) {  // stage A-half of tile t+3
      __builtin_amdgcn_global_load_lds((const GLOBAL_AS void*)(gA0 + ko),
                                       (LDS_AS void*)(&sA[slw][ch0]), 16, 0, 0);
      __builtin_amdgcn_global_load_lds((const GLOBAL_AS void*)(gA1 + ko),
                                       (LDS_AS void*)(&sA[slw][ch1]), 16, 0, 0);
    }
    __builtin_amdgcn_s_barrier();
    asm volatile("s_waitcnt lgkmcnt(0)" ::: "memory");
    __builtin_amdgcn_sched_barrier(0);
    __builtin_amdgcn_s_setprio(1);
#pragma unroll
    for (int mf = 0; mf < 4; ++mf)
#pragma unroll
      for (int nf = 0; nf < 4; ++nf)
        acc[mf][nf] = __builtin_amdgcn_mfma_f32_16x16x32_bf16(
            af0[mf], bfr[nf], acc[mf][nf], 0, 0, 0);
    __builtin_amdgcn_s_setprio(0);
    __builtin_amdgcn_s_barrier();

    // ================= phase 1: frags {mf4-7 x nf0-3} ======================
#pragma unroll
    for (int mf = 0; mf < 4; ++mf)
      af1[mf] = *(const bf16x8*)&sA[sl][aoff + (mf + 4) * 512];
    if (st) {  // stage B-half of tile t+3
      __builtin_amdgcn_global_load_lds((const GLOBAL_AS void*)(gB0 + ko),
                                       (LDS_AS void*)(&sB[slw][ch0]), 16, 0, 0);
      __builtin_amdgcn_global_load_lds((const GLOBAL_AS void*)(gB1 + ko),
                                       (LDS_AS void*)(&sB[slw][ch1]), 16, 0, 0);
    }
    __builtin_amdgcn_s_barrier();
    asm volatile("s_waitcnt lgkmcnt(0)" ::: "memory");
    __builtin_amdgcn_sched_barrier(0);
    __builtin_amdgcn_s_setprio(1);
#pragma unroll
    for (int mf = 0; mf < 4; ++mf)
#pragma unroll
      for (int nf = 0; nf < 4; ++nf)
        acc[mf + 4][nf] = __builtin_amdgcn_mfma_f32_16x16x32_bf16(
            af1[mf], bfr[nf], acc[mf + 4][nf], 0, 0, 0);
    __builtin_amdgcn_s_setprio(0);

    // gate: k-tile t+1 must be resident for the next iteration; keep the 2
    // newest k-tiles (8 loads) in flight across the barrier (T4, no drain).
    if (t < NT - 1) {
      if (t + 3 < NT) {
        asm volatile("s_waitcnt vmcnt(8)" ::: "memory");
      } else if (t + 3 == NT) {
        asm volatile("s_waitcnt vmcnt(4)" ::: "memory");
      } else {
        asm volatile("s_waitcnt vmcnt(0)" ::: "memory");
      }
      __builtin_amdgcn_s_barrier();
      asm volatile("" ::: "memory");
    }
  }
#undef STAGE_ALL

  // ---- epilogue: 16x16 C/D layout col = lane&15, row = (lane>>4)*4 + r
#pragma unroll
  for (int nf = 0; nf < 4; ++nf) {
    const int n = (int)n0 + wn * 64 + nf * 16 + (lane & 15);
    const float bv = bias[n];
#pragma unroll
    for (int mf = 0; mf < 8; ++mf) {
      const size_t mb = m0 + wm * 128 + mf * 16 + (lane >> 4) * 4;
#pragma unroll
      for (int r = 0; r < 4; ++r) {
        C[(mb + r) * N_DIM + n] = acc[mf][nf][r] + bv;
      }
    }
  }
}

// ---------------- fallback (only if ws too small) -------------------------
__global__ void fallback_kernel(const float* __restrict__ x,
                                const int* __restrict__ wq,
                                const float* __restrict__ wscale,
                                const float* __restrict__ bias,
                                float* __restrict__ out) {
  __shared__ float xs[K_DIM];
  const size_t m = blockIdx.x;
  for (int k = threadIdx.x; k < K_DIM; k += 256) xs[k] = x[m * K_DIM + k];
  __syncthreads();
  for (int n = threadIdx.x; n < N_DIM; n += 256) {
    const int* wr = wq + (size_t)n * K_DIM;
    float s = 0.f;
    for (int k = 0; k < K_DIM; ++k) s += xs[k] * (float)wr[k];
    out[m * N_DIM + n] = s * wscale[n] + bias[n];
  }
}

extern "C" void kernel_launch(void* const* d_in, const int* in_sizes, int n_in,
                              void* d_out, int out_size, void* d_ws, size_t ws_size,
                              hipStream_t stream) {
  const float* x       = (const float*)d_in[0];
  const int*   w_q     = (const int*)d_in[1];
  const float* w_scale = (const float*)d_in[2];
  const float* bias    = (const float*)d_in[3];
  const float* lora_A  = (const float*)d_in[4];
  const float* lora_S  = (const float*)d_in[5];
  const float* lora_B  = (const float*)d_in[6];
  float* out = (float*)d_out;

  const size_t need = ((size_t)M_DIM + N_DIM) * K_DIM * sizeof(unsigned short); // 96 MB
  if (ws_size < need) {
    fallback_kernel<<<M_DIM, 256, 0, stream>>>(x, w_q, w_scale, bias, out);
    return;
  }

  unsigned short* Xbf = (unsigned short*)d_ws;
  unsigned short* Wbf = Xbf + (size_t)M_DIM * K_DIM;

  cast_kernel<<<M_DIM * K_DIM / (256 * 8), 256, 0, stream>>>(x, Xbf);
  fold_kernel<<<(N_DIM / 4) * (K_DIM / 2048), 256, 0, stream>>>(
      w_q, w_scale, lora_A, lora_S, lora_B, Wbf);
  gemm_bias_kernel<<<dim3((N_DIM / BN) * (M_DIM / BM)), 512, 0, stream>>>(
      Xbf, Wbf, bias, out);
}

// Round 3
// 527.202 us; speedup vs baseline: 1.0677x; 1.0677x over previous
//
#include <hip/hip_runtime.h>

// SVDQuantLinear: out[m,n] = x[m,:] . (w_q[n,:]*w_scale[n]) + bias[n] + lora
// Fold rank-32 LoRA into dequantized W (fp32, one bf16 round) -> one bf16 GEMM.
// R1: XOR-swizzled LDS, R2: 32x32x16 + fused prep.
// R3: 256x256/BK=32 ring, counted vmcnt(8), setprio, XCD swizzle ->
//     conflicts 0, MfmaUtil 48%, gemm 350->258us.
// R4 FAILED: 2-phase split -> 298us/40% (4 barriers + 2 full lgkm drains per
//     K-tile; coarse phase-split without full m201 machinery hurts = m196).
// R5 (this round): R3 schedule, but REMOVE the forced lgkmcnt(0)+
//     sched_barrier(0) before the MFMA cluster. Those are only needed for
//     inline-asm ds_read (rule #18); our LDS reads are compiler-visible, so
//     hipcc emits fine-grained counted lgkmcnt per dependent MFMA (m97 asm)
//     and interleaves read-waits INTO the MFMA cluster. The explicit drain
//     was serializing ~12 reads ahead of every 32-MFMA cluster.
//     Also: cast+fold re-fused into one prep_kernel (one launch fewer).

#define M_DIM 8192   // B*S
#define N_DIM 4096   // D_OUT
#define K_DIM 4096   // D_IN
#define R_DIM 32

#define BM 256
#define BN 256
#define BK 32                 // 64 B per row in LDS
#define NT (K_DIM / BK)       // 128 k-tiles
#define NSLOT 4               // LDS ring depth: 4 * (16KB A + 16KB B) = 128 KiB

typedef short bf16x8 __attribute__((ext_vector_type(8)));
typedef float f32x4 __attribute__((ext_vector_type(4)));
typedef unsigned short u16x8 __attribute__((ext_vector_type(8)));

#define GLOBAL_AS __attribute__((address_space(1)))
#define LDS_AS __attribute__((address_space(3)))

__device__ __forceinline__ unsigned short f2bf(float f) {
  union { float f; unsigned u; } v;
  v.f = f;
  unsigned u = v.u;
  u += 0x7fffu + ((u >> 16) & 1u);  // RNE (finite inputs)
  return (unsigned short)(u >> 16);
}

// ---------------- fused prep: cast x -> bf16 AND fold W_eff -> bf16 --------
// blocks [0, 16384): cast 2048 x-elems each (float4 -> bf16x8).
// blocks [16384, 18432): fold 4 o-rows x 2048 i-cols of
//   W_eff = wq*scale + lora_B*diag(S)*lora_A.
#define CAST_BLOCKS 16384
__global__ void prep_kernel(const float* __restrict__ x,
                            const int* __restrict__ wq,
                            const float* __restrict__ wscale,
                            const float* __restrict__ lA,
                            const float* __restrict__ lS,
                            const float* __restrict__ lB,
                            unsigned short* __restrict__ Xbf,
                            unsigned short* __restrict__ Wbf) {
  __shared__ float bs[4][32];
  const int tid = threadIdx.x;

  if (blockIdx.x < CAST_BLOCKS) {
    size_t i = ((size_t)blockIdx.x * 256 + tid) * 8;
    float4 v0 = *(const float4*)(x + i);
    float4 v1 = *(const float4*)(x + i + 4);
    u16x8 o;
    o[0] = f2bf(v0.x); o[1] = f2bf(v0.y); o[2] = f2bf(v0.z); o[3] = f2bf(v0.w);
    o[4] = f2bf(v1.x); o[5] = f2bf(v1.y); o[6] = f2bf(v1.z); o[7] = f2bf(v1.w);
    *(u16x8*)(Xbf + i) = o;
    return;
  }

  const int bid2 = (int)blockIdx.x - CAST_BLOCKS;   // 0..2047
  const int o0 = (bid2 >> 1) * 4;                   // 1024 o-blocks x 4 rows
  const int i0 = (bid2 & 1) * 2048 + tid * 8;       // 2 i-blocks

  if (tid < 128) {
    int o = tid >> 5, r = tid & 31;
    bs[o][r] = lB[(size_t)(o0 + o) * R_DIM + r] * lS[r];
  }
  __syncthreads();

  float acc[4][8];
#pragma unroll
  for (int o = 0; o < 4; ++o)
#pragma unroll
    for (int j = 0; j < 8; ++j) acc[o][j] = 0.f;

  for (int r = 0; r < R_DIM; ++r) {
    float4 a0 = *(const float4*)(lA + (size_t)r * K_DIM + i0);
    float4 a1 = *(const float4*)(lA + (size_t)r * K_DIM + i0 + 4);
    float av[8] = {a0.x, a0.y, a0.z, a0.w, a1.x, a1.y, a1.z, a1.w};
#pragma unroll
    for (int o = 0; o < 4; ++o) {
      float b = bs[o][r];
#pragma unroll
      for (int j = 0; j < 8; ++j) acc[o][j] += b * av[j];
    }
  }

#pragma unroll
  for (int o = 0; o < 4; ++o) {
    float sc = wscale[o0 + o];
    const int* qp = wq + (size_t)(o0 + o) * K_DIM + i0;
    int4 q0 = *(const int4*)qp;
    int4 q1 = *(const int4*)(qp + 4);
    int qv[8] = {q0.x, q0.y, q0.z, q0.w, q1.x, q1.y, q1.z, q1.w};
    u16x8 ov;
#pragma unroll
    for (int j = 0; j < 8; ++j) ov[j] = f2bf(acc[o][j] + (float)qv[j] * sc);
    *(u16x8*)(Wbf + (size_t)(o0 + o) * K_DIM + i0) = ov;
  }
}

// ---------------- main GEMM: C = Xbf * Wbf^T + bias ------------------------
// 256x256 tile, BK=32, 512 thr = 8 waves (2M x 4N), wave = 128x64 output =
// 8x4 frags of 16x16x32 MFMA. 4-slot LDS ring; stage t+3 while computing t;
// counted vmcnt(8) gate once per K-tile (2 k-tiles in flight across barriers).
// LDS: 16B line (row, sl) holds k-group g = sl ^ ((row>>1)&3); staging keeps
// LDS dest linear and permutes the per-lane GLOBAL k-offset (rule #21).
// NO explicit lgkm drain: compiler emits counted lgkmcnt per MFMA operand,
// interleaving read-waits into the MFMA cluster.
__global__ __launch_bounds__(512, 2) void gemm_bias_kernel(
    const unsigned short* __restrict__ A,   // [M, K] bf16 bits
    const unsigned short* __restrict__ B,   // [N, K] bf16 bits
    const float* __restrict__ bias,         // [N]
    float* __restrict__ C) {                // [M, N]
  __shared__ __align__(16) unsigned short sA[NSLOT][BM * BK];  // 4 x 16 KiB
  __shared__ __align__(16) unsigned short sB[NSLOT][BN * BK];  // 4 x 16 KiB

  const int tid = threadIdx.x;
  const int lane = tid & 63;
  const int wv = tid >> 6;      // 0..7
  const int wm = wv >> 2;       // 0..1
  const int wn = wv & 3;        // 0..3

  // T1: bijective XCD swizzle (grid = 512 = 8*64). XCD x owns 2 B-panels.
  const int bid = (int)blockIdx.x;
  const int s = ((bid & 7) << 6) + (bid >> 3);
  const int bn_ = s >> 5;       // 0..15
  const int bm_ = s & 31;       // 0..31
  const size_t m0 = (size_t)bm_ * BM;
  const size_t n0 = (size_t)bn_ * BN;

  // ---- staging: lane l -> local row l>>2, 16B slot l&3,
  // global k-group (l&3)^((l>>3)&3); LDS dest linear (wave-uniform base).
  const int lrow = lane >> 2;                                  // 0..15
  const int gsl = (((lane & 3) ^ ((lane >> 3) & 3))) * 8;      // k elems
  const int r0 = (wv * 2) * 16 + lrow;                         // chunk c=0 row
  const unsigned short* gA0 = A + (m0 + r0) * (size_t)K_DIM + gsl;
  const unsigned short* gA1 = gA0 + 16 * (size_t)K_DIM;
  const unsigned short* gB0 = B + (n0 + r0) * (size_t)K_DIM + gsl;
  const unsigned short* gB1 = gB0 + 16 * (size_t)K_DIM;
  const int ch0 = (wv * 2 + 0) * 512;   // LDS chunk bases (shorts, 1KB each)
  const int ch1 = (wv * 2 + 1) * 512;

#define STAGE_ALL(kt, sl_)                                                    \
  do {                                                                        \
    const size_t ko = (size_t)(kt)*BK;                                        \
    __builtin_amdgcn_global_load_lds((const GLOBAL_AS void*)(gA0 + ko),       \
                                     (LDS_AS void*)(&sA[sl_][ch0]), 16, 0, 0);\
    __builtin_amdgcn_global_load_lds((const GLOBAL_AS void*)(gA1 + ko),       \
                                     (LDS_AS void*)(&sA[sl_][ch1]), 16, 0, 0);\
    __builtin_amdgcn_global_load_lds((const GLOBAL_AS void*)(gB0 + ko),       \
                                     (LDS_AS void*)(&sB[sl_][ch0]), 16, 0, 0);\
    __builtin_amdgcn_global_load_lds((const GLOBAL_AS void*)(gB1 + ko),       \
                                     (LDS_AS void*)(&sB[sl_][ch1]), 16, 0, 0);\
  } while (0)

  // ---- read addressing (16x16x32 frag: m = lane&15, k = (lane>>4)*8+j)
  const int rdrow = lane & 15;
  const int slot4 = (lane >> 4) ^ ((lane >> 1) & 3);           // swizzled slot
  const int aoff = (wm * 128 + rdrow) * BK + slot4 * 8;        // + mf*512
  const int boff = (wn * 64 + rdrow) * BK + slot4 * 8;         // + nf*512

  f32x4 acc[8][4];
#pragma unroll
  for (int mf = 0; mf < 8; ++mf)
#pragma unroll
    for (int nf = 0; nf < 4; ++nf) acc[mf][nf] = (f32x4){0.f, 0.f, 0.f, 0.f};

  // ---- prologue: 3 k-tiles in flight; wait only for tile 0 (vmcnt(8)).
  STAGE_ALL(0, 0);
  STAGE_ALL(1, 1);
  STAGE_ALL(2, 2);
  asm volatile("s_waitcnt vmcnt(8)" ::: "memory");
  __builtin_amdgcn_s_barrier();
  asm volatile("" ::: "memory");

  for (int t = 0; t < NT; ++t) {
    const int sl = t & 3;
    bf16x8 af[8], bfr[4];
    // issue B-frags first, then A-frags: first MFMAs (af[0] x bfr[*]) depend
    // on the oldest reads -> compiler's counted lgkm overlaps the rest.
#pragma unroll
    for (int nf = 0; nf < 4; ++nf)
      bfr[nf] = *(const bf16x8*)&sB[sl][boff + nf * 512];
#pragma unroll
    for (int mf = 0; mf < 8; ++mf)
      af[mf] = *(const bf16x8*)&sA[sl][aoff + mf * 512];

    if (t + 3 < NT) STAGE_ALL(t + 3, (t + 3) & 3);  // overwrites slot (t-1)&3

    __builtin_amdgcn_s_setprio(1);
#pragma unroll
    for (int mf = 0; mf < 8; ++mf)
#pragma unroll
      for (int nf = 0; nf < 4; ++nf)
        acc[mf][nf] = __builtin_amdgcn_mfma_f32_16x16x32_bf16(
            af[mf], bfr[nf], acc[mf][nf], 0, 0, 0);
    __builtin_amdgcn_s_setprio(0);

    // gate: k-tile t+1 must be resident for the next iteration; keep the 2
    // newest k-tiles (8 loads) in flight across the barrier (T4, no drain).
    // All slot-sl reads retired before their consumer MFMAs above, so the
    // wave crossing this barrier cannot race the t+4 staging next iter.
    if (t < NT - 1) {
      if (t + 3 < NT) {
        asm volatile("s_waitcnt vmcnt(8)" ::: "memory");
      } else if (t + 3 == NT) {
        asm volatile("s_waitcnt vmcnt(4)" ::: "memory");
      } else {
        asm volatile("s_waitcnt vmcnt(0)" ::: "memory");
      }
      __builtin_amdgcn_s_barrier();
      asm volatile("" ::: "memory");
    }
  }
#undef STAGE_ALL

  // ---- epilogue: 16x16 C/D layout col = lane&15, row = (lane>>4)*4 + r
#pragma unroll
  for (int nf = 0; nf < 4; ++nf) {
    const int n = (int)n0 + wn * 64 + nf * 16 + (lane & 15);
    const float bv = bias[n];
#pragma unroll
    for (int mf = 0; mf < 8; ++mf) {
      const size_t mb = m0 + wm * 128 + mf * 16 + (lane >> 4) * 4;
#pragma unroll
      for (int r = 0; r < 4; ++r) {
        C[(mb + r) * N_DIM + n] = acc[mf][nf][r] + bv;
      }
    }
  }
}

// ---------------- fallback (only if ws too small) -------------------------
__global__ void fallback_kernel(const float* __restrict__ x,
                                const int* __restrict__ wq,
                                const float* __restrict__ wscale,
                                const float* __restrict__ bias,
                                float* __restrict__ out) {
  __shared__ float xs[K_DIM];
  const size_t m = blockIdx.x;
  for (int k = threadIdx.x; k < K_DIM; k += 256) xs[k] = x[m * K_DIM + k];
  __syncthreads();
  for (int n = threadIdx.x; n < N_DIM; n += 256) {
    const int* wr = wq + (size_t)n * K_DIM;
    float s = 0.f;
    for (int k = 0; k < K_DIM; ++k) s += xs[k] * (float)wr[k];
    out[m * N_DIM + n] = s * wscale[n] + bias[n];
  }
}

extern "C" void kernel_launch(void* const* d_in, const int* in_sizes, int n_in,
                              void* d_out, int out_size, void* d_ws, size_t ws_size,
                              hipStream_t stream) {
  const float* x       = (const float*)d_in[0];
  const int*   w_q     = (const int*)d_in[1];
  const float* w_scale = (const float*)d_in[2];
  const float* bias    = (const float*)d_in[3];
  const float* lora_A  = (const float*)d_in[4];
  const float* lora_S  = (const float*)d_in[5];
  const float* lora_B  = (const float*)d_in[6];
  float* out = (float*)d_out;

  const size_t need = ((size_t)M_DIM + N_DIM) * K_DIM * sizeof(unsigned short); // 96 MB
  if (ws_size < need) {
    fallback_kernel<<<M_DIM, 256, 0, stream>>>(x, w_q, w_scale, bias, out);
    return;
  }

  unsigned short* Xbf = (unsigned short*)d_ws;
  unsigned short* Wbf = Xbf + (size_t)M_DIM * K_DIM;

  prep_kernel<<<CAST_BLOCKS + (N_DIM / 4) * (K_DIM / 2048), 256, 0, stream>>>(
      x, w_q, w_scale, lora_A, lora_S, lora_B, Xbf, Wbf);
  gemm_bias_kernel<<<dim3((N_DIM / BN) * (M_DIM / BM)), 512, 0, stream>>>(
      Xbf, Wbf, bias, out);
}